// Round 3
// baseline (1225.402 us; speedup 1.0000x reference)
//
#include <hip/hip_runtime.h>
#include <math.h>

// Problem constants
#define BN   4
#define CN   256
#define HN   128
#define WN   128
#define COMP 64
#define KK   25      // K*K taps
#define HO   64
#define WO   64
#define NW   16      // waves per fused block
#define CPW  (CN / NW)  // 16 channels per wave
#define WSTRIDE 240  // padded w2c row stride (floats), 960 B, 16B-aligned

// Workspace (floats): w2c[256][WSTRIDE], tb[225]
#define TB_OFF (256 * WSTRIDE)

// ---------------------------------------------------------------------------
// Kernel A: compose w2c[c][m*9+t] = sum_k w2[m,k,t] * w1[k,c]  (padded rows),
// tb[m*9+t] = sum_k w2[m,k,t] * b1[k].  One block per mt, one thread per c.
// ---------------------------------------------------------------------------
__global__ __launch_bounds__(256) void compose_w(
    const float* __restrict__ w1, const float* __restrict__ b1,
    const float* __restrict__ w2, float* __restrict__ ws) {
  int mt = blockIdx.x;             // 0..224
  int c  = threadIdx.x;            // 0..255
  float acc = 0.f;
#pragma unroll 8
  for (int k = 0; k < COMP; ++k)
    acc += w2[(size_t)(mt / 9 * COMP + k) * 9 + (mt % 9)] * w1[k * CN + c];
  ws[c * WSTRIDE + mt] = acc;
  if (mt < WSTRIDE - 225)          // zero the row padding (cols 225..239)
    ws[c * WSTRIDE + 225 + mt] = 0.f;
  if (c == 0) {
    float tbv = 0.f;
    for (int k = 0; k < COMP; ++k)
      tbv += w2[(size_t)(mt / 9 * COMP + k) * 9 + (mt % 9)] * b1[k];
    ws[TB_OFF + mt] = tbv;
  }
}

// ---------------------------------------------------------------------------
// Fused: composed conv3x3(stride2) -> softmax(25) -> CARAFE 5x5 gather.
// Grid (HO, BN), 1024 threads = 16 waves; wave wv owns 16 channels, lane = wo.
// Weights stream global->VGPR->LDS (per-wave double buffer), consumed as
// wave-uniform ds_read broadcasts. No scalar loads / no SMEM in the hot loop.
// ---------------------------------------------------------------------------
__global__ __launch_bounds__(1024, 4) void fused_kernel(
    const float* __restrict__ x, const float* __restrict__ b2,
    const float* __restrict__ ws, float* __restrict__ out) {
  const int ho  = blockIdx.x;
  const int b   = blockIdx.y;
  const int tid = threadIdx.x;
  const int wo  = tid & 63;
  const int wv  = tid >> 6;                        // 0..15
  const int c_base = __builtin_amdgcn_readfirstlane(wv * CPW);

  const float* __restrict__ w2c = ws;
  const float* __restrict__ tb  = ws + TB_OFF;

  __shared__ float red[8 * KK * 64];               // 51200 B
  __shared__ float wbuf[NW][2][WSTRIDE];           // 30720 B
  __shared__ float sm[KK * 64];                    //  6400 B

  const float* __restrict__ xb = x + (size_t)(b * CN) * (HN * WN);
  const int col = 2 * wo;

  // ---------------- Phase 1: conv rows 2ho-1..2ho+1 ----------------
  float acc[KK];
#pragma unroll
  for (int m = 0; m < KK; ++m) acc[m] = 0.f;

  float2 xbuf[2][3];
  auto load_ch = [&](int ci, float2* dst) {
    const float* xc = xb + (size_t)(c_base + ci) * (HN * WN);
    dst[0] = (ho > 0) ? *(const float2*)(xc + (2 * ho - 1) * WN + col)
                      : make_float2(0.f, 0.f);
    dst[1] = *(const float2*)(xc + (2 * ho) * WN + col);
    dst[2] = *(const float2*)(xc + (2 * ho + 1) * WN + col);
  };
  // weight staging: lane < 57 carries 4 floats (228 >= 225)
  auto wload = [&](int ci) -> float4 {
    if (wo < 57)
      return *(const float4*)(w2c + (size_t)(c_base + ci) * WSTRIDE + wo * 4);
    return make_float4(0.f, 0.f, 0.f, 0.f);
  };

  load_ch(0, xbuf[0]);
  load_ch(1, xbuf[1]);
  {
    float4 w0 = wload(0), w1v = wload(1);
    if (wo < 57) {
      *(float4*)&wbuf[wv][0][wo * 4] = w0;
      *(float4*)&wbuf[wv][1][wo * 4] = w1v;
    }
  }

  const float wok = (wo > 0) ? 1.f : 0.f;
  for (int ci = 0; ci < CPW; ++ci) {
    float2 r0 = xbuf[ci & 1][0], r1 = xbuf[ci & 1][1], r2 = xbuf[ci & 1][2];
    if (ci + 2 < CPW) load_ch(ci + 2, xbuf[ci & 1]);
    float4 wnext = (ci + 2 < CPW) ? wload(ci + 2)
                                  : make_float4(0.f, 0.f, 0.f, 0.f);

    float xv[9];
    xv[0] = wok * __shfl_up(r0.y, 1, 64); xv[1] = r0.x; xv[2] = r0.y;
    xv[3] = wok * __shfl_up(r1.y, 1, 64); xv[4] = r1.x; xv[5] = r1.y;
    xv[6] = wok * __shfl_up(r2.y, 1, 64); xv[7] = r2.x; xv[8] = r2.y;

    const float* __restrict__ wrow = &wbuf[wv][ci & 1][0];
#pragma unroll
    for (int m = 0; m < KK; ++m) {
      float a = acc[m];
#pragma unroll
      for (int t = 0; t < 9; ++t) a += wrow[m * 9 + t] * xv[t];
      acc[m] = a;
    }
    // refill the slot we just finished reading (in-order per-wave DS pipe)
    if (ci + 2 < CPW && wo < 57) *(float4*)&wbuf[wv][ci & 1][wo * 4] = wnext;
  }

  // Pre-issue gather-phase x loads so they fly during reduction + softmax
  float2 g[2][5];
  auto load_g = [&](int ci, float2* dst) {
    const float* xc = xb + (size_t)(c_base + ci) * (HN * WN);
#pragma unroll
    for (int i = 0; i < 5; ++i) {
      int r = 2 * ho - 2 + i;
      dst[i] = (r >= 0 && r < HN) ? *(const float2*)(xc + r * WN + col)
                                  : make_float2(0.f, 0.f);
    }
  };
  load_g(0, g[0]);
  load_g(1, g[1]);

  // ---------------- Reduction across 16 waves ----------------
  if (wv >= 8) {
#pragma unroll
    for (int m = 0; m < KK; ++m) red[((wv - 8) * KK + m) * 64 + wo] = acc[m];
  }
  __syncthreads();
  if (wv < 8) {
#pragma unroll
    for (int m = 0; m < KK; ++m) red[(wv * KK + m) * 64 + wo] += acc[m];
  }
  __syncthreads();
  if (wv < 4) {
#pragma unroll
    for (int m = 0; m < KK; ++m)
      red[(wv * KK + m) * 64 + wo] += red[((wv + 4) * KK + m) * 64 + wo];
  }
  __syncthreads();
  if (wv < 2) {
#pragma unroll
    for (int m = 0; m < KK; ++m)
      red[(wv * KK + m) * 64 + wo] += red[((wv + 2) * KK + m) * 64 + wo];
  }
  __syncthreads();

  // ---------------- Softmax (one wave) ----------------
  if (tid < 64) {
    const float vr0 = (ho > 0) ? 1.f : 0.f;   // row 2ho-1 validity
    const float vq0 = (wo > 0) ? 1.f : 0.f;   // col 2wo-1 validity
    float logit[KK];
    float mx = -1e30f;
#pragma unroll
    for (int m = 0; m < KK; ++m) {
      const float* t9 = tb + m * 9;
      float l = b2[m]
              + vr0 * (vq0 * t9[0] + t9[1] + t9[2])
              +       (vq0 * t9[3] + t9[4] + t9[5])
              +       (vq0 * t9[6] + t9[7] + t9[8]);
      l += red[(0 * KK + m) * 64 + wo] + red[(1 * KK + m) * 64 + wo];
      logit[m] = l;
      mx = fmaxf(mx, l);
    }
    float s = 0.f;
#pragma unroll
    for (int m = 0; m < KK; ++m) {
      float e = __expf(logit[m] - mx);
      logit[m] = e;
      s += e;
    }
    float inv = 1.f / s;
#pragma unroll
    for (int m = 0; m < KK; ++m) sm[m * 64 + wo] = logit[m] * inv;
  }
  __syncthreads();

  // ---------------- Phase 2: CARAFE gather rows 2ho-2..2ho+2 ----------
  float smr[KK];
#pragma unroll
  for (int m = 0; m < KK; ++m) smr[m] = sm[m * 64 + wo];

  const float w63 = (wo < 63) ? 1.f : 0.f;
  for (int ci = 0; ci < CPW; ++ci) {
    float2 v[5];
#pragma unroll
    for (int i = 0; i < 5; ++i) v[i] = g[ci & 1][i];
    if (ci + 2 < CPW) load_g(ci + 2, g[ci & 1]);

    float acc2 = 0.f;
#pragma unroll
    for (int i = 0; i < 5; ++i) {
      float lx = wok * __shfl_up(v[i].x, 1, 64);    // col 2wo-2
      float ly = wok * __shfl_up(v[i].y, 1, 64);    // col 2wo-1
      float rx = w63 * __shfl_down(v[i].x, 1, 64);  // col 2wo+2
      acc2 += lx * smr[i * 5 + 0] + ly * smr[i * 5 + 1]
            + v[i].x * smr[i * 5 + 2] + v[i].y * smr[i * 5 + 3]
            + rx * smr[i * 5 + 4];
    }
    out[(((size_t)(b * CN + c_base + ci)) * HO + ho) * WO + wo] = acc2;
  }
}

// ---------------------------------------------------------------------------
extern "C" void kernel_launch(void* const* d_in, const int* in_sizes, int n_in,
                              void* d_out, int out_size, void* d_ws, size_t ws_size,
                              hipStream_t stream) {
  const float* x  = (const float*)d_in[0];
  const float* w1 = (const float*)d_in[1];
  const float* b1 = (const float*)d_in[2];
  const float* w2 = (const float*)d_in[3];
  const float* b2 = (const float*)d_in[4];
  float* out = (float*)d_out;
  float* ws  = (float*)d_ws;

  hipLaunchKernelGGL(compose_w, dim3(225), dim3(256), 0, stream, w1, b1, w2, ws);
  hipLaunchKernelGGL(fused_kernel, dim3(HO, BN), dim3(1024), 0, stream,
                     x, b2, ws, out);
}

// Round 4
// 248.611 us; speedup vs baseline: 4.9290x; 4.9290x over previous
//
#include <hip/hip_runtime.h>
#include <math.h>

// Problem constants
#define BN   4
#define CN   256
#define HN   128
#define WN   128
#define COMP 64
#define KK   25      // K*K taps
#define HO   64
#define WO   64
#define NW   16      // waves per block
#define NZ   2       // channel splits (blocks per (b,ho) for conv)
#define CPW  (CN / NZ / NW)   // 8 channels per wave
#define WSTRIDE 240  // padded w2c row stride (floats)

// Workspace (floats): w2c[256][240], tb[225(+31)], pl[2][4][64][25][64]
#define TB_OFF  (256 * WSTRIDE)
#define PL_OFF  (TB_OFF + 256)
#define PL_SLICE (BN * HO * KK * WO)   // per-z slice elements

// ---------------------------------------------------------------------------
// Kernel A: compose w2c[c][m*9+t] = sum_k w2[m,k,t]*w1[k,c]; tb[m*9+t] =
// sum_k w2[m,k,t]*b1[k]. One block per mt, one thread per c.
// ---------------------------------------------------------------------------
__global__ __launch_bounds__(256) void compose_w(
    const float* __restrict__ w1, const float* __restrict__ b1,
    const float* __restrict__ w2, float* __restrict__ ws) {
  int mt = blockIdx.x;             // 0..224
  int c  = threadIdx.x;            // 0..255
  float acc = 0.f;
#pragma unroll 8
  for (int k = 0; k < COMP; ++k)
    acc += w2[(size_t)(mt / 9 * COMP + k) * 9 + (mt % 9)] * w1[k * CN + c];
  ws[c * WSTRIDE + mt] = acc;
  if (mt < WSTRIDE - 225)          // zero row padding
    ws[c * WSTRIDE + 225 + mt] = 0.f;
  if (c == 0) {
    float tbv = 0.f;
    for (int k = 0; k < COMP; ++k)
      tbv += w2[(size_t)(mt / 9 * COMP + k) * 9 + (mt % 9)] * b1[k];
    ws[TB_OFF + mt] = tbv;
  }
}

// ---------------------------------------------------------------------------
// Kernel B: composed conv3x3 stride2 -> partial logits (one channel half).
// Grid (HO, BN, NZ), 1024 threads = 16 waves; wave owns 8 channels; lane = wo.
// NO DS ops in the hot loop: cols 2wo-1..2wo+1 come from two aligned float2
// loads (at 2wo-2 and 2wo). Weights stream on the scalar pipe (wave-uniform).
// ---------------------------------------------------------------------------
__global__ __launch_bounds__(1024, 4) void conv_kernel(
    const float* __restrict__ x, const float* __restrict__ ws,
    float* __restrict__ pl) {
  const int ho  = blockIdx.x;
  const int b   = blockIdx.y;
  const int z   = blockIdx.z;
  const int tid = threadIdx.x;
  const int wo  = tid & 63;
  const int wv  = tid >> 6;                        // 0..15
  const int c_base = __builtin_amdgcn_readfirstlane(z * (CN / NZ) + wv * CPW);

  const float* __restrict__ w2c = ws;
  __shared__ float red[8 * KK * 64];               // 51200 B

  const float* __restrict__ xb = x + (size_t)(b * CN) * (HN * WN);
  const int colL = (wo > 0) ? (2 * wo - 2) : 0;    // aligned float2 (8B)
  const int colR = 2 * wo;
  const float wok = (wo > 0) ? 1.f : 0.f;

  float acc[KK];
#pragma unroll
  for (int m = 0; m < KK; ++m) acc[m] = 0.f;

  // per-channel: rows 2ho-1(valid if ho>0), 2ho, 2ho+1; 2 float2 each
  float2 xq[2][3][2];
  auto load_ch = [&](int ci, float2 dst[3][2]) {
    const float* xc = xb + (size_t)(c_base + ci) * (HN * WN);
    if (ho > 0) {
      dst[0][0] = *(const float2*)(xc + (2 * ho - 1) * WN + colL);
      dst[0][1] = *(const float2*)(xc + (2 * ho - 1) * WN + colR);
    } else {
      dst[0][0] = make_float2(0.f, 0.f);
      dst[0][1] = make_float2(0.f, 0.f);
    }
    dst[1][0] = *(const float2*)(xc + (2 * ho) * WN + colL);
    dst[1][1] = *(const float2*)(xc + (2 * ho) * WN + colR);
    dst[2][0] = *(const float2*)(xc + (2 * ho + 1) * WN + colL);
    dst[2][1] = *(const float2*)(xc + (2 * ho + 1) * WN + colR);
  };
  load_ch(0, xq[0]);
  load_ch(1, xq[1]);

  for (int ci = 0; ci < CPW; ++ci) {
    float xv[9];
#pragma unroll
    for (int r = 0; r < 3; ++r) {
      float2 lo = xq[ci & 1][r][0], hi = xq[ci & 1][r][1];
      xv[r * 3 + 0] = wok * lo.y;   // col 2wo-1
      xv[r * 3 + 1] = hi.x;         // col 2wo
      xv[r * 3 + 2] = hi.y;         // col 2wo+1
    }
    if (ci + 2 < CPW) load_ch(ci + 2, xq[ci & 1]);

    const float* __restrict__ wrow = w2c + (size_t)(c_base + ci) * WSTRIDE;
#pragma unroll
    for (int m = 0; m < KK; ++m) {
      float a = acc[m];
#pragma unroll
      for (int t = 0; t < 9; ++t) a += wrow[m * 9 + t] * xv[t];
      acc[m] = a;
    }
  }

  // 16 -> 8 -> 4 -> 2 wave reduction in LDS, wave 0 stores partial logits
  if (wv >= 8) {
#pragma unroll
    for (int m = 0; m < KK; ++m) red[((wv - 8) * KK + m) * 64 + wo] = acc[m];
  }
  __syncthreads();
  if (wv < 8) {
#pragma unroll
    for (int m = 0; m < KK; ++m) red[(wv * KK + m) * 64 + wo] += acc[m];
  }
  __syncthreads();
  if (wv < 4) {
#pragma unroll
    for (int m = 0; m < KK; ++m)
      red[(wv * KK + m) * 64 + wo] += red[((wv + 4) * KK + m) * 64 + wo];
  }
  __syncthreads();
  if (wv < 2) {
#pragma unroll
    for (int m = 0; m < KK; ++m)
      red[(wv * KK + m) * 64 + wo] += red[((wv + 2) * KK + m) * 64 + wo];
  }
  __syncthreads();
  if (tid < 64) {
    float* dst = pl + (size_t)z * PL_SLICE +
                 (((size_t)b * HO + ho) * KK) * 64;
#pragma unroll
    for (int m = 0; m < KK; ++m)
      dst[m * 64 + wo] = red[(0 * KK + m) * 64 + wo] +
                         red[(1 * KK + m) * 64 + wo];
  }
}

// ---------------------------------------------------------------------------
// Kernel C: softmax(25) + CARAFE 5x5 gather (one channel half per block).
// Grid (HO, BN, NZ), 1024 threads = 16 waves, 8 channels/wave.
// ---------------------------------------------------------------------------
__global__ __launch_bounds__(1024, 4) void gather_kernel(
    const float* __restrict__ x, const float* __restrict__ b2,
    const float* __restrict__ ws, const float* __restrict__ pl,
    float* __restrict__ out) {
  const int ho  = blockIdx.x;
  const int b   = blockIdx.y;
  const int z   = blockIdx.z;
  const int tid = threadIdx.x;
  const int wo  = tid & 63;
  const int wv  = tid >> 6;
  const int c_base = __builtin_amdgcn_readfirstlane(z * (CN / NZ) + wv * CPW);

  const float* __restrict__ tb = ws + TB_OFF;
  __shared__ float sm[KK * 64];                    // 6400 B

  const float* __restrict__ xb = x + (size_t)(b * CN) * (HN * WN);
  const int col = 2 * wo;
  const float wok = (wo > 0) ? 1.f : 0.f;
  const float w63 = (wo < 63) ? 1.f : 0.f;

  // pre-issue gather x loads so they fly during softmax
  float2 g[2][5];
  auto load_g = [&](int ci, float2* dst) {
    const float* xc = xb + (size_t)(c_base + ci) * (HN * WN);
#pragma unroll
    for (int i = 0; i < 5; ++i) {
      int r = 2 * ho - 2 + i;
      dst[i] = (r >= 0 && r < HN) ? *(const float2*)(xc + r * WN + col)
                                  : make_float2(0.f, 0.f);
    }
  };
  load_g(0, g[0]);
  load_g(1, g[1]);

  if (tid < 64) {
    const float vr0 = (ho > 0) ? 1.f : 0.f;   // row 2ho-1 validity
    const float vq0 = (wo > 0) ? 1.f : 0.f;   // col 2wo-1 validity
    const float* p0 = pl + (((size_t)b * HO + ho) * KK) * 64;
    const float* p1 = p0 + PL_SLICE;
    float logit[KK];
    float mx = -1e30f;
#pragma unroll
    for (int m = 0; m < KK; ++m) {
      const float* t9 = tb + m * 9;
      float l = b2[m]
              + vr0 * (vq0 * t9[0] + t9[1] + t9[2])
              +       (vq0 * t9[3] + t9[4] + t9[5])
              +       (vq0 * t9[6] + t9[7] + t9[8]);
      l += p0[m * 64 + wo] + p1[m * 64 + wo];
      logit[m] = l;
      mx = fmaxf(mx, l);
    }
    float s = 0.f;
#pragma unroll
    for (int m = 0; m < KK; ++m) {
      float e = __expf(logit[m] - mx);
      logit[m] = e;
      s += e;
    }
    float inv = 1.f / s;
#pragma unroll
    for (int m = 0; m < KK; ++m) sm[m * 64 + wo] = logit[m] * inv;
  }
  __syncthreads();

  float smr[KK];
#pragma unroll
  for (int m = 0; m < KK; ++m) smr[m] = sm[m * 64 + wo];

  for (int ci = 0; ci < CPW; ++ci) {
    float2 v[5];
#pragma unroll
    for (int i = 0; i < 5; ++i) v[i] = g[ci & 1][i];
    if (ci + 2 < CPW) load_g(ci + 2, g[ci & 1]);

    float acc2 = 0.f;
#pragma unroll
    for (int i = 0; i < 5; ++i) {
      float lx = wok * __shfl_up(v[i].x, 1, 64);    // col 2wo-2
      float ly = wok * __shfl_up(v[i].y, 1, 64);    // col 2wo-1
      float rx = w63 * __shfl_down(v[i].x, 1, 64);  // col 2wo+2
      acc2 += lx * smr[i * 5 + 0] + ly * smr[i * 5 + 1]
            + v[i].x * smr[i * 5 + 2] + v[i].y * smr[i * 5 + 3]
            + rx * smr[i * 5 + 4];
    }
    out[(((size_t)(b * CN + c_base + ci)) * HO + ho) * WO + wo] = acc2;
  }
}

// ---------------------------------------------------------------------------
extern "C" void kernel_launch(void* const* d_in, const int* in_sizes, int n_in,
                              void* d_out, int out_size, void* d_ws, size_t ws_size,
                              hipStream_t stream) {
  const float* x  = (const float*)d_in[0];
  const float* w1 = (const float*)d_in[1];
  const float* b1 = (const float*)d_in[2];
  const float* w2 = (const float*)d_in[3];
  const float* b2 = (const float*)d_in[4];
  float* out = (float*)d_out;
  float* ws  = (float*)d_ws;
  float* pl  = ws + PL_OFF;

  hipLaunchKernelGGL(compose_w, dim3(225), dim3(256), 0, stream, w1, b1, w2, ws);
  hipLaunchKernelGGL(conv_kernel, dim3(HO, BN, NZ), dim3(1024), 0, stream,
                     x, ws, pl);
  hipLaunchKernelGGL(gather_kernel, dim3(HO, BN, NZ), dim3(1024), 0, stream,
                     x, b2, ws, pl, out);
}

// Round 5
// 165.215 us; speedup vs baseline: 7.4170x; 1.5048x over previous
//
#include <hip/hip_runtime.h>
#include <math.h>

// Problem constants
#define BN   4
#define CN   256
#define HN   128
#define WN   128
#define COMP 64
#define KK   25      // K*K taps
#define HO   64
#define WO   64

// ---------------- fast-path workspace layout (float offsets) ----------------
// wA   : 9*16*64*8 bf16 A-fragments      = 36864 floats (147456 B)
// tb   : 225 floats (+pad to 256)
// pl   : 2 * BN*HO*KK*64 partial logits  = 819200 floats
// xT   : BN*HN*WN*CN bf16 (NHWC)         = 8388608 float-slots
#define TB_OFF    36864
#define PL_OFF    37120
#define PL_SLICE  (BN * HO * KK * 64)          // 409600
#define XT_OFF    (PL_OFF + 2 * PL_SLICE)      // 856320
#define WS_NEED   ((size_t)(XT_OFF + (size_t)BN * HN * WN * CN / 2) * 4)

typedef short v8s  __attribute__((ext_vector_type(8)));
typedef float v16f __attribute__((ext_vector_type(16)));

__device__ inline ushort f2bf(float f) {       // fp32 -> bf16 bits, RNE
  unsigned u = __float_as_uint(f);
  return (ushort)((u + 0x7fffu + ((u >> 16) & 1u)) >> 16);
}

// ---------------------------------------------------------------------------
// Compose: bake w2*w1 directly into MFMA A-fragment order (bf16) + tb.
// Grid (9 taps, 16 chunks), 64 threads. lane: m=lane&31, half=lane>>5.
// wA[((t*16+chunk)*64+lane)*8 + j] = W_t[c = chunk*16+half*8+j][m]  (m<25)
// ---------------------------------------------------------------------------
__global__ __launch_bounds__(64) void compose_mfma(
    const float* __restrict__ w1, const float* __restrict__ b1,
    const float* __restrict__ w2, float* __restrict__ ws) {
  const int t = blockIdx.x, chunk = blockIdx.y;
  const int lane = threadIdx.x;
  const int m = lane & 31, half = lane >> 5;
  const int c0 = chunk * 16 + half * 8;
  float acc[8] = {0.f, 0.f, 0.f, 0.f, 0.f, 0.f, 0.f, 0.f};
  if (m < KK) {
    for (int k = 0; k < COMP; ++k) {
      float wv = w2[(size_t)(m * COMP + k) * 9 + t];
      const float* w1r = w1 + (size_t)k * CN + c0;
      float4 a = *(const float4*)w1r;
      float4 bq = *(const float4*)(w1r + 4);
      acc[0] += wv * a.x;  acc[1] += wv * a.y;
      acc[2] += wv * a.z;  acc[3] += wv * a.w;
      acc[4] += wv * bq.x; acc[5] += wv * bq.y;
      acc[6] += wv * bq.z; acc[7] += wv * bq.w;
    }
  }
  ushort* wA = (ushort*)ws;
  ushort pk[8];
#pragma unroll
  for (int j = 0; j < 8; ++j) pk[j] = f2bf(acc[j]);
  *(ushort4*)(wA + ((size_t)(t * 16 + chunk) * 64 + lane) * 8) =
      make_ushort4(pk[0], pk[1], pk[2], pk[3]);
  *(ushort4*)(wA + ((size_t)(t * 16 + chunk) * 64 + lane) * 8 + 4) =
      make_ushort4(pk[4], pk[5], pk[6], pk[7]);
  if (chunk == 0 && lane < KK) {
    float tbv = 0.f;
    for (int k = 0; k < COMP; ++k)
      tbv += w2[(size_t)(lane * COMP + k) * 9 + t] * b1[k];
    ws[TB_OFF + lane * 9 + t] = tbv;
  }
}

// ---------------------------------------------------------------------------
// Transpose x NCHW fp32 -> xT NHWC bf16. Grid (8, HN, BN), 256 threads.
// blockIdx.x = wt(2) | ct(4): 64x64 (c x w) tile via LDS.
// ---------------------------------------------------------------------------
__global__ __launch_bounds__(256) void transpose_x(
    const float* __restrict__ x, float* __restrict__ ws) {
  __shared__ float st[64][65];
  const int wt = blockIdx.x & 1, ct = blockIdx.x >> 1;
  const int h = blockIdx.y, b = blockIdx.z;
  const int tid = threadIdx.x;
  const int w0 = wt * 64, c0 = ct * 64;
  {
    const int wl = tid & 63, cw = tid >> 6;    // cw 0..3
#pragma unroll
    for (int i = 0; i < 16; ++i) {
      int cl = cw * 16 + i;
      st[cl][wl] = x[((size_t)(b * CN + c0 + cl) * HN + h) * WN + w0 + wl];
    }
  }
  __syncthreads();
  ushort* xT = (ushort*)(ws + XT_OFF);
  const int cg = tid & 15, wl0 = tid >> 4;     // 16 c-groups x 16 w
#pragma unroll
  for (int wi = 0; wi < 4; ++wi) {
    int wl = wl0 + wi * 16;
    ushort4 o = make_ushort4(f2bf(st[cg * 4 + 0][wl]), f2bf(st[cg * 4 + 1][wl]),
                             f2bf(st[cg * 4 + 2][wl]), f2bf(st[cg * 4 + 3][wl]));
    *(ushort4*)(xT + ((size_t)((b * HN + h) * WN + w0 + wl)) * CN + c0 + cg * 4) = o;
  }
}

// ---------------------------------------------------------------------------
// MFMA conv: 9 tap-GEMMs, 32(m) x 32(pixels) tile per wave, K=128 (z-half).
// Grid (4 = wt|z<<1, HO, BN), 64 threads. Partial logits -> pl[z].
// C/D layout: col(pixel)=lane&31, row(m)=(reg&3)+8*(reg>>2)+4*(lane>>5).
// ---------------------------------------------------------------------------
__global__ __launch_bounds__(64) void conv_mfma(
    const float* __restrict__ ws, float* __restrict__ pl) {
  const int wt = blockIdx.x & 1, z = blockIdx.x >> 1;
  const int ho = blockIdx.y, b = blockIdx.z;
  const int lane = threadIdx.x;
  const int n = lane & 31, half = lane >> 5;
  const int wo = wt * 32 + n;
  const ushort* xT = (const ushort*)(ws + XT_OFF);
  const ushort* wA = (const ushort*)ws;
  const int coff = z * 128 + half * 8;
  const v8s zero8 = {};
  v16f acc = {};

#pragma unroll
  for (int dr = 0; dr < 3; ++dr) {
    const int r = 2 * ho + dr - 1;
    if (r < 0) continue;                       // wave-uniform (ho==0, dr==0)
#pragma unroll
    for (int dc = 0; dc < 3; ++dc) {
      const int t = dr * 3 + dc;
      const int q = 2 * wo + dc - 1;
      const bool bad = q < 0;                  // only lane wo==0, dc==0
      const int qc = bad ? 0 : q;
      const ushort* bp = xT + ((size_t)((b * HN + r) * WN + qc)) * CN + coff;
      const ushort* ap = wA + ((size_t)(t * 16 + z * 8) * 64 + lane) * 8;
      v8s bf[8], af[8];
#pragma unroll
      for (int cc = 0; cc < 8; ++cc) {
        bf[cc] = *(const v8s*)(bp + cc * 16);
        af[cc] = *(const v8s*)(ap + (size_t)cc * 512);
      }
      if (dc == 0) {
#pragma unroll
        for (int cc = 0; cc < 8; ++cc) bf[cc] = bad ? zero8 : bf[cc];
      }
#pragma unroll
      for (int cc = 0; cc < 8; ++cc)
        acc = __builtin_amdgcn_mfma_f32_32x32x16_bf16(af[cc], bf[cc], acc, 0, 0, 0);
    }
  }

  float* dst = pl + (size_t)z * PL_SLICE + ((size_t)(b * HO + ho) * KK) * 64 + wo;
#pragma unroll
  for (int rg = 0; rg < 16; ++rg) {
    int m = (rg & 3) + 8 * (rg >> 2) + 4 * half;
    if (m < KK) dst[(size_t)m * 64] = acc[rg];
  }
}

// ---------------------------------------------------------------------------
// Softmax(25) + CARAFE 5x5 gather (round-4 proven code; fp32 x).
// Grid (HO, BN, 2), 1024 threads = 16 waves, 8 channels/wave.
// ---------------------------------------------------------------------------
__global__ __launch_bounds__(1024, 4) void gather_kernel(
    const float* __restrict__ x, const float* __restrict__ b2,
    const float* __restrict__ tb, const float* __restrict__ pl,
    float* __restrict__ out) {
  const int ho  = blockIdx.x;
  const int b   = blockIdx.y;
  const int z   = blockIdx.z;
  const int tid = threadIdx.x;
  const int wo  = tid & 63;
  const int wv  = tid >> 6;
  const int c_base = __builtin_amdgcn_readfirstlane(z * (CN / 2) + wv * 8);

  __shared__ float sm[KK * 64];

  const float* __restrict__ xb = x + (size_t)(b * CN) * (HN * WN);
  const int col = 2 * wo;
  const float wok = (wo > 0) ? 1.f : 0.f;
  const float w63 = (wo < 63) ? 1.f : 0.f;

  float2 g[2][5];
  auto load_g = [&](int ci, float2* dst) {
    const float* xc = xb + (size_t)(c_base + ci) * (HN * WN);
#pragma unroll
    for (int i = 0; i < 5; ++i) {
      int r = 2 * ho - 2 + i;
      dst[i] = (r >= 0 && r < HN) ? *(const float2*)(xc + r * WN + col)
                                  : make_float2(0.f, 0.f);
    }
  };
  load_g(0, g[0]);
  load_g(1, g[1]);

  if (tid < 64) {
    const float vr0 = (ho > 0) ? 1.f : 0.f;
    const float vq0 = (wo > 0) ? 1.f : 0.f;
    const float* p0 = pl + (((size_t)b * HO + ho) * KK) * 64;
    const float* p1 = p0 + PL_SLICE;
    float logit[KK];
    float mx = -1e30f;
#pragma unroll
    for (int m = 0; m < KK; ++m) {
      const float* t9 = tb + m * 9;
      float l = b2[m]
              + vr0 * (vq0 * t9[0] + t9[1] + t9[2])
              +       (vq0 * t9[3] + t9[4] + t9[5])
              +       (vq0 * t9[6] + t9[7] + t9[8]);
      l += p0[m * 64 + wo] + p1[m * 64 + wo];
      logit[m] = l;
      mx = fmaxf(mx, l);
    }
    float s = 0.f;
#pragma unroll
    for (int m = 0; m < KK; ++m) {
      float e = __expf(logit[m] - mx);
      logit[m] = e;
      s += e;
    }
    float inv = 1.f / s;
#pragma unroll
    for (int m = 0; m < KK; ++m) sm[m * 64 + wo] = logit[m] * inv;
  }
  __syncthreads();

  float smr[KK];
#pragma unroll
  for (int m = 0; m < KK; ++m) smr[m] = sm[m * 64 + wo];

  for (int ci = 0; ci < 8; ++ci) {
    float2 v[5];
#pragma unroll
    for (int i = 0; i < 5; ++i) v[i] = g[ci & 1][i];
    if (ci + 2 < 8) load_g(ci + 2, g[ci & 1]);

    float acc2 = 0.f;
#pragma unroll
    for (int i = 0; i < 5; ++i) {
      float lx = wok * __shfl_up(v[i].x, 1, 64);
      float ly = wok * __shfl_up(v[i].y, 1, 64);
      float rx = w63 * __shfl_down(v[i].x, 1, 64);
      acc2 += lx * smr[i * 5 + 0] + ly * smr[i * 5 + 1]
            + v[i].x * smr[i * 5 + 2] + v[i].y * smr[i * 5 + 3]
            + rx * smr[i * 5 + 4];
    }
    out[(((size_t)(b * CN + c_base + ci)) * HO + ho) * WO + wo] = acc2;
  }
}

// ============================ FALLBACK PATH ================================
// Round-2 proven kernels (used only if ws_size < WS_NEED).
#define FB_WSTRIDE 240
#define FB_TB_OFF  (256 * FB_WSTRIDE)

__global__ __launch_bounds__(256) void compose_w_fb(
    const float* __restrict__ w1, const float* __restrict__ b1,
    const float* __restrict__ w2, float* __restrict__ ws) {
  int mt = blockIdx.x, c = threadIdx.x;
  float acc = 0.f;
#pragma unroll 8
  for (int k = 0; k < COMP; ++k)
    acc += w2[(size_t)(mt / 9 * COMP + k) * 9 + (mt % 9)] * w1[k * CN + c];
  ws[c * FB_WSTRIDE + mt] = acc;
  if (mt < FB_WSTRIDE - 225) ws[c * FB_WSTRIDE + 225 + mt] = 0.f;
  if (c == 0) {
    float tbv = 0.f;
    for (int k = 0; k < COMP; ++k)
      tbv += w2[(size_t)(mt / 9 * COMP + k) * 9 + (mt % 9)] * b1[k];
    ws[FB_TB_OFF + mt] = tbv;
  }
}

__global__ __launch_bounds__(1024, 4) void fused_fb(
    const float* __restrict__ x, const float* __restrict__ b2,
    const float* __restrict__ ws, float* __restrict__ out) {
  const int ho = blockIdx.x, b = blockIdx.y, tid = threadIdx.x;
  const int wo = tid & 63, wv = tid >> 6;
  const int c_base = __builtin_amdgcn_readfirstlane(wv * 16);
  const float* __restrict__ w2c = ws;
  const float* __restrict__ tb  = ws + FB_TB_OFF;
  __shared__ float red[8 * KK * 64];
  __shared__ float sm[KK * 64];
  const float* __restrict__ xb = x + (size_t)(b * CN) * (HN * WN);
  const int col = 2 * wo;
  float acc[KK];
#pragma unroll
  for (int m = 0; m < KK; ++m) acc[m] = 0.f;
  float2 xbuf[2][3];
  auto load_ch = [&](int ci, float2* dst) {
    const float* xc = xb + (size_t)(c_base + ci) * (HN * WN);
    dst[0] = (ho > 0) ? *(const float2*)(xc + (2 * ho - 1) * WN + col)
                      : make_float2(0.f, 0.f);
    dst[1] = *(const float2*)(xc + (2 * ho) * WN + col);
    dst[2] = *(const float2*)(xc + (2 * ho + 1) * WN + col);
  };
  load_ch(0, xbuf[0]);
  load_ch(1, xbuf[1]);
  const float wok = (wo > 0) ? 1.f : 0.f;
  for (int ci = 0; ci < 16; ++ci) {
    float2 r0 = xbuf[ci & 1][0], r1 = xbuf[ci & 1][1], r2 = xbuf[ci & 1][2];
    if (ci + 2 < 16) load_ch(ci + 2, xbuf[ci & 1]);
    float xv[9];
    xv[0] = wok * __shfl_up(r0.y, 1, 64); xv[1] = r0.x; xv[2] = r0.y;
    xv[3] = wok * __shfl_up(r1.y, 1, 64); xv[4] = r1.x; xv[5] = r1.y;
    xv[6] = wok * __shfl_up(r2.y, 1, 64); xv[7] = r2.x; xv[8] = r2.y;
    const float* __restrict__ wrow = w2c + (size_t)(c_base + ci) * FB_WSTRIDE;
#pragma unroll
    for (int m = 0; m < KK; ++m) {
      float a = acc[m];
#pragma unroll
      for (int t = 0; t < 9; ++t) a += wrow[m * 9 + t] * xv[t];
      acc[m] = a;
    }
  }
  float2 g[2][5];
  auto load_g = [&](int ci, float2* dst) {
    const float* xc = xb + (size_t)(c_base + ci) * (HN * WN);
#pragma unroll
    for (int i = 0; i < 5; ++i) {
      int r = 2 * ho - 2 + i;
      dst[i] = (r >= 0 && r < HN) ? *(const float2*)(xc + r * WN + col)
                                  : make_float2(0.f, 0.f);
    }
  };
  load_g(0, g[0]);
  load_g(1, g[1]);
  if (wv >= 8) {
#pragma unroll
    for (int m = 0; m < KK; ++m) red[((wv - 8) * KK + m) * 64 + wo] = acc[m];
  }
  __syncthreads();
  if (wv < 8) {
#pragma unroll
    for (int m = 0; m < KK; ++m) red[(wv * KK + m) * 64 + wo] += acc[m];
  }
  __syncthreads();
  if (wv < 4) {
#pragma unroll
    for (int m = 0; m < KK; ++m)
      red[(wv * KK + m) * 64 + wo] += red[((wv + 4) * KK + m) * 64 + wo];
  }
  __syncthreads();
  if (wv < 2) {
#pragma unroll
    for (int m = 0; m < KK; ++m)
      red[(wv * KK + m) * 64 + wo] += red[((wv + 2) * KK + m) * 64 + wo];
  }
  __syncthreads();
  if (tid < 64) {
    const float vr0 = (ho > 0) ? 1.f : 0.f;
    const float vq0 = (wo > 0) ? 1.f : 0.f;
    float logit[KK];
    float mx = -1e30f;
#pragma unroll
    for (int m = 0; m < KK; ++m) {
      const float* t9 = tb + m * 9;
      float l = b2[m]
              + vr0 * (vq0 * t9[0] + t9[1] + t9[2])
              +       (vq0 * t9[3] + t9[4] + t9[5])
              +       (vq0 * t9[6] + t9[7] + t9[8]);
      l += red[(0 * KK + m) * 64 + wo] + red[(1 * KK + m) * 64 + wo];
      logit[m] = l;
      mx = fmaxf(mx, l);
    }
    float s = 0.f;
#pragma unroll
    for (int m = 0; m < KK; ++m) {
      float e = __expf(logit[m] - mx);
      logit[m] = e;
      s += e;
    }
    float inv = 1.f / s;
#pragma unroll
    for (int m = 0; m < KK; ++m) sm[m * 64 + wo] = logit[m] * inv;
  }
  __syncthreads();
  float smr[KK];
#pragma unroll
  for (int m = 0; m < KK; ++m) smr[m] = sm[m * 64 + wo];
  const float w63 = (wo < 63) ? 1.f : 0.f;
  for (int ci = 0; ci < 16; ++ci) {
    float2 v[5];
#pragma unroll
    for (int i = 0; i < 5; ++i) v[i] = g[ci & 1][i];
    if (ci + 2 < 16) load_g(ci + 2, g[ci & 1]);
    float acc2 = 0.f;
#pragma unroll
    for (int i = 0; i < 5; ++i) {
      float lx = wok * __shfl_up(v[i].x, 1, 64);
      float ly = wok * __shfl_up(v[i].y, 1, 64);
      float rx = w63 * __shfl_down(v[i].x, 1, 64);
      acc2 += lx * smr[i * 5 + 0] + ly * smr[i * 5 + 1]
            + v[i].x * smr[i * 5 + 2] + v[i].y * smr[i * 5 + 3]
            + rx * smr[i * 5 + 4];
    }
    out[(((size_t)(b * CN + c_base + ci)) * HO + ho) * WO + wo] = acc2;
  }
}

// ---------------------------------------------------------------------------
extern "C" void kernel_launch(void* const* d_in, const int* in_sizes, int n_in,
                              void* d_out, int out_size, void* d_ws, size_t ws_size,
                              hipStream_t stream) {
  const float* x  = (const float*)d_in[0];
  const float* w1 = (const float*)d_in[1];
  const float* b1 = (const float*)d_in[2];
  const float* w2 = (const float*)d_in[3];
  const float* b2 = (const float*)d_in[4];
  float* out = (float*)d_out;
  float* ws  = (float*)d_ws;

  if (ws_size >= WS_NEED) {
    float* pl = ws + PL_OFF;
    hipLaunchKernelGGL(compose_mfma, dim3(9, 16), dim3(64), 0, stream,
                       w1, b1, w2, ws);
    hipLaunchKernelGGL(transpose_x, dim3(8, HN, BN), dim3(256), 0, stream,
                       x, ws);
    hipLaunchKernelGGL(conv_mfma, dim3(4, HO, BN), dim3(64), 0, stream,
                       ws, pl);
    hipLaunchKernelGGL(gather_kernel, dim3(HO, BN, 2), dim3(1024), 0, stream,
                       x, b2, ws + TB_OFF, pl, out);
  } else {
    hipLaunchKernelGGL(compose_w_fb, dim3(225), dim3(256), 0, stream,
                       w1, b1, w2, ws);
    hipLaunchKernelGGL(fused_fb, dim3(HO, BN), dim3(1024), 0, stream,
                       x, b2, ws, out);
  }
}